// Round 8
// baseline (755.894 us; speedup 1.0000x reference)
//
#include <hip/hip_runtime.h>
#include <hip/hip_fp16.h>

// APPNP: K steps of D^{-1/2} A D^{-1/2} propagation + teleport, then MLP.
// R8: prop processes 8 consecutive nodes per wave as ONE contiguous edge
// stream (CSR padded to 4-aligned node boundaries), 4-wide batches with a
// 2-stage software pipeline; node-boundary flushes are wave-uniform. This
// amortizes the row_ptr->ew->gather dependency chain over ~76 edges instead
// of ~9.5 (R7 was latency-chain-bound: 4.4 TB/s gather vs >15 TB/s ceiling).

#define N_NODES 100000
#define N_EDGES 800000
#define D_DATA  100
#define H_DIM   256
#define N_CLS   47
#define K_STEPS 10
#define ALPHA   0.1f
#define HS      128      // fp16 h row stride (halfs); cols 100..127 are zero
#define NPW     8        // nodes per wave in prop

#define SCAN_NB    200
#define SCAN_CHUNK 500   // 200*500 == N_NODES
#define EW_CAP (N_EDGES + 3 * N_NODES)   // padded-CSR worst case

// ---------------- CSR build ----------------

__global__ void deg_kernel(const int* __restrict__ dst, int* __restrict__ deg, int e) {
    int i = blockIdx.x * blockDim.x + threadIdx.x;
    if (i < e) atomicAdd(&deg[dst[i]], 1);
}

// pass 1: per-block sums of padded deg (round up to multiple of 4)
__global__ __launch_bounds__(256) void scan_partial_kernel(
        const int* __restrict__ deg, int* __restrict__ partials) {
    __shared__ int red[256];
    int t = threadIdx.x;
    int base = blockIdx.x * SCAN_CHUNK;
    int s = 0;
    int i0 = 2 * t, i1 = 2 * t + 1;
    if (i0 < SCAN_CHUNK) s += (deg[base + i0] + 3) & ~3;
    if (i1 < SCAN_CHUNK) s += (deg[base + i1] + 3) & ~3;
    red[t] = s;
    __syncthreads();
    for (int off = 128; off > 0; off >>= 1) {
        if (t < off) red[t] += red[t + off];
        __syncthreads();
    }
    if (t == 0) partials[blockIdx.x] = red[0];
}

// pass 2: single block scans the 200 partials (exclusive); total -> row_ptr[N]
__global__ __launch_bounds__(256) void scan_top_kernel(
        const int* __restrict__ partials, int* __restrict__ pofs,
        int* __restrict__ row_ptr) {
    __shared__ int s[256];
    int t = threadIdx.x;
    s[t] = (t < SCAN_NB) ? partials[t] : 0;
    __syncthreads();
    for (int off = 1; off < 256; off <<= 1) {
        int v = (t >= off) ? s[t - off] : 0;
        __syncthreads();
        s[t] += v;
        __syncthreads();
    }
    if (t < SCAN_NB) pofs[t] = s[t] - partials[t];
    if (t == SCAN_NB - 1) row_ptr[N_NODES] = s[t];   // padded total
}

// pass 3: block-local exclusive scan of padded deg + emit row_ptr and norm
__global__ __launch_bounds__(256) void scan_emit_kernel(
        const int* __restrict__ deg, const int* __restrict__ pofs,
        int* __restrict__ row_ptr, float* __restrict__ norm) {
    __shared__ int s[256];
    int t = threadIdx.x;
    int base = blockIdx.x * SCAN_CHUNK;
    int i0 = 2 * t, i1 = 2 * t + 1;
    int d0 = (i0 < SCAN_CHUNK) ? deg[base + i0] : 0;
    int d1 = (i1 < SCAN_CHUNK) ? deg[base + i1] : 0;
    int p0 = (d0 + 3) & ~3, p1 = (d1 + 3) & ~3;
    s[t] = p0 + p1;
    __syncthreads();
    for (int off = 1; off < 256; off <<= 1) {
        int v = (t >= off) ? s[t - off] : 0;
        __syncthreads();
        s[t] += v;
        __syncthreads();
    }
    int p = s[t] - (p0 + p1) + pofs[blockIdx.x];
    if (i0 < SCAN_CHUNK) {
        row_ptr[base + i0] = p;
        norm[base + i0] = rsqrtf((float)max(d0, 1));
    }
    if (i1 < SCAN_CHUNK) {
        row_ptr[base + i1] = p + p0;
        norm[base + i1] = rsqrtf((float)max(d1, 1));
    }
}

__global__ void scatter_kernel(const int* __restrict__ src, const int* __restrict__ dst,
                               const float* __restrict__ norm,
                               const int* __restrict__ row_ptr, int* __restrict__ fill,
                               float2* __restrict__ ew, int e) {
    int i = blockIdx.x * blockDim.x + threadIdx.x;
    if (i < e) {
        int d = dst[i], s = src[i];
        int pos = row_ptr[d] + atomicAdd(&fill[d], 1);
        float w = (1.0f - ALPHA) * norm[s] * norm[d];
        ew[pos] = make_float2(w, __int_as_float(s));
    }
}

// fill pad slots [row_ptr[i]+deg[i], row_ptr[i+1]) with weight-0 edges to node 0
__global__ void pad_kernel(const int* __restrict__ deg, const int* __restrict__ row_ptr,
                           float2* __restrict__ ew, int n) {
    int i = blockIdx.x * blockDim.x + threadIdx.x;
    if (i < n) {
        int b = row_ptr[i] + deg[i];
        int e = row_ptr[i + 1];
        for (int s = b; s < e; ++s) ew[s] = make_float2(0.f, __int_as_float(0));
    }
}

__global__ void transpose_w2_kernel(const float* __restrict__ W2, float* __restrict__ W2t) {
    int idx = blockIdx.x * blockDim.x + threadIdx.x;
    if (idx < 48 * H_DIM) {
        int c = idx >> 8;
        int j = idx & (H_DIM - 1);
        W2t[c * H_DIM + j] = (c < N_CLS) ? W2[j * N_CLS + c] : 0.f;
    }
}

// x (fp32, dense stride 100) -> x16 (fp16, stride 128, zero pad cols)
__global__ void convert_x16_kernel(const float* __restrict__ x,
                                   __half2* __restrict__ x16, int n_half2) {
    int i = blockIdx.x * blockDim.x + threadIdx.x;
    if (i < n_half2) {
        int node = i >> 6;          // 64 half2 per row
        int c2 = i & 63;            // half2 index in row
        float2 v = make_float2(0.f, 0.f);
        if (c2 < D_DATA / 2) {
            const float2* r = (const float2*)(x + (size_t)node * D_DATA);
            v = r[c2];
        }
        x16[i] = __float22half2_rn(v);
    }
}

// ---------------- propagation ----------------
// One wave handles NPW consecutive nodes = one contiguous, 4-aligned edge
// stream. 4-wide batches, 2-stage rotation (prefetch i+1 while consuming i).
// Node-boundary flush is wave-uniform; empty nodes handled by while-flush.

__global__ __launch_bounds__(256) void prop16_kernel(
        const __half* __restrict__ hin, const float* __restrict__ x,
        const int* __restrict__ row_ptr, const float2* __restrict__ ew,
        __half* __restrict__ hout, int n_nodes) {
    int lane = threadIdx.x & 63;
    int wave = blockIdx.x * 4 + (threadIdx.x >> 6);
    int n0 = __builtin_amdgcn_readfirstlane(wave * NPW);
    if (n0 >= n_nodes) return;
    int e0   = __builtin_amdgcn_readfirstlane(row_ptr[n0]);
    int eend = __builtin_amdgcn_readfirstlane(row_ptr[n0 + NPW]);
    bool xact = lane < (D_DATA / 2);

    int ni = 0;                                        // node cursor (0..NPW)
    int rp_next = __builtin_amdgcn_readfirstlane(row_ptr[n0 + 1]);
    float ax = 0.f, ay = 0.f;
    float2 pw[4]; __half2 gv[4];
    if (e0 < eend) {
#pragma unroll
        for (int j = 0; j < 4; ++j) pw[j] = ew[e0 + j];
#pragma unroll
        for (int j = 0; j < 4; ++j)
            gv[j] = ((const __half2*)(hin + (size_t)__float_as_int(pw[j].y) * HS))[lane];
    }
    for (int e = e0; e < eend; e += 4) {
        float2 pwn[4]; __half2 gvn[4];
        bool more = (e + 4) < eend;
        if (more) {
#pragma unroll
            for (int j = 0; j < 4; ++j) pwn[j] = ew[e + 4 + j];
#pragma unroll
            for (int j = 0; j < 4; ++j)
                gvn[j] = ((const __half2*)(hin + (size_t)__float_as_int(pwn[j].y) * HS))[lane];
        }
        // flush any node(s) whose edge list ends at e (wave-uniform cond)
        while (e == rp_next && ni < NPW) {
            float2 xv = make_float2(0.f, 0.f);
            if (xact) xv = ((const float2*)(x + (size_t)(n0 + ni) * D_DATA))[lane];
            float2 o = make_float2(ax + ALPHA * xv.x, ay + ALPHA * xv.y);
            ((__half2*)(hout + (size_t)(n0 + ni) * HS))[lane] = __float22half2_rn(o);
            ax = 0.f; ay = 0.f;
            ++ni;
            rp_next = __builtin_amdgcn_readfirstlane(row_ptr[n0 + ni + 1 > NPW ? NPW : n0 == n0 ? ni + 1 : ni + 1]);
            rp_next = __builtin_amdgcn_readfirstlane(row_ptr[n0 + (ni < NPW ? ni + 1 : NPW)]);
        }
        // consume current batch
#pragma unroll
        for (int j = 0; j < 4; ++j) {
            float2 v = __half22float2(gv[j]);
            ax += pw[j].x * v.x; ay += pw[j].x * v.y;
        }
#pragma unroll
        for (int j = 0; j < 4; ++j) { pw[j] = pwn[j]; gv[j] = gvn[j]; }
    }
    // flush remaining nodes (last real node + trailing empties)
    while (ni < NPW) {
        float2 xv = make_float2(0.f, 0.f);
        if (xact) xv = ((const float2*)(x + (size_t)(n0 + ni) * D_DATA))[lane];
        float2 o = make_float2(ax + ALPHA * xv.x, ay + ALPHA * xv.y);
        ((__half2*)(hout + (size_t)(n0 + ni) * HS))[lane] = __float22half2_rn(o);
        ax = 0.f; ay = 0.f;
        ++ni;
    }
}

// final step: same structure, fp32 dense output for the MLP
__global__ __launch_bounds__(256) void prop_final_kernel(
        const __half* __restrict__ hin, const float* __restrict__ x,
        const int* __restrict__ row_ptr, const float2* __restrict__ ew,
        float* __restrict__ hout, int n_nodes) {
    int lane = threadIdx.x & 63;
    int wave = blockIdx.x * 4 + (threadIdx.x >> 6);
    int n0 = __builtin_amdgcn_readfirstlane(wave * NPW);
    if (n0 >= n_nodes) return;
    int e0   = __builtin_amdgcn_readfirstlane(row_ptr[n0]);
    int eend = __builtin_amdgcn_readfirstlane(row_ptr[n0 + NPW]);
    bool xact = lane < (D_DATA / 2);

    int ni = 0;
    int rp_next = __builtin_amdgcn_readfirstlane(row_ptr[n0 + 1]);
    float ax = 0.f, ay = 0.f;
    float2 pw[4]; __half2 gv[4];
    if (e0 < eend) {
#pragma unroll
        for (int j = 0; j < 4; ++j) pw[j] = ew[e0 + j];
#pragma unroll
        for (int j = 0; j < 4; ++j)
            gv[j] = ((const __half2*)(hin + (size_t)__float_as_int(pw[j].y) * HS))[lane];
    }
    for (int e = e0; e < eend; e += 4) {
        float2 pwn[4]; __half2 gvn[4];
        bool more = (e + 4) < eend;
        if (more) {
#pragma unroll
            for (int j = 0; j < 4; ++j) pwn[j] = ew[e + 4 + j];
#pragma unroll
            for (int j = 0; j < 4; ++j)
                gvn[j] = ((const __half2*)(hin + (size_t)__float_as_int(pwn[j].y) * HS))[lane];
        }
        while (e == rp_next && ni < NPW) {
            if (xact) {
                float2 xv = ((const float2*)(x + (size_t)(n0 + ni) * D_DATA))[lane];
                float2 o = make_float2(ax + ALPHA * xv.x, ay + ALPHA * xv.y);
                ((float2*)(hout + (size_t)(n0 + ni) * D_DATA))[lane] = o;
            }
            ax = 0.f; ay = 0.f;
            ++ni;
            rp_next = __builtin_amdgcn_readfirstlane(row_ptr[n0 + (ni < NPW ? ni + 1 : NPW)]);
        }
#pragma unroll
        for (int j = 0; j < 4; ++j) {
            float2 v = __half22float2(gv[j]);
            ax += pw[j].x * v.x; ay += pw[j].x * v.y;
        }
#pragma unroll
        for (int j = 0; j < 4; ++j) { pw[j] = pwn[j]; gv[j] = gvn[j]; }
    }
    while (ni < NPW) {
        if (xact) {
            float2 xv = ((const float2*)(x + (size_t)(n0 + ni) * D_DATA))[lane];
            float2 o = make_float2(ax + ALPHA * xv.x, ay + ALPHA * xv.y);
            ((float2*)(hout + (size_t)(n0 + ni) * D_DATA))[lane] = o;
        }
        ax = 0.f; ay = 0.f;
        ++ni;
    }
}

// ---------------- fused MLP (unchanged from R5-R7) ----------------

#define TN 32
#define HP 260

__global__ __launch_bounds__(256, 4) void mlp_kernel(
        const float* __restrict__ h,
        const float* __restrict__ W1, const float* __restrict__ b1,
        const float* __restrict__ W2t, const float* __restrict__ b2,
        float* __restrict__ out, int n_nodes) {
    __shared__ float zs[TN][HP];   // 32.5 KB -> 4 blocks/CU
    int tid = threadIdx.x;
    int node0 = blockIdx.x * TN;

    // ---- phase 1: z = relu(h @ W1 + b1) ----
    {
        int cg = tid & 63;
        int ng = tid >> 6;
        const float4* hrow[8];
#pragma unroll
        for (int i = 0; i < 8; ++i) {
            int r = __builtin_amdgcn_readfirstlane(node0 + ng * 8 + i);
            hrow[i] = (const float4*)(h + (size_t)r * D_DATA);
        }
        float acc[8][4];
        float4 bv = *(const float4*)(b1 + 4 * cg);
#pragma unroll
        for (int i = 0; i < 8; ++i) {
            acc[i][0] = bv.x; acc[i][1] = bv.y; acc[i][2] = bv.z; acc[i][3] = bv.w;
        }
        float4 wv[4], wn[4];
#pragma unroll
        for (int k = 0; k < 4; ++k)
            wv[k] = *(const float4*)&W1[(size_t)k * H_DIM + 4 * cg];
        for (int d4 = 0; d4 < D_DATA / 4; ++d4) {
            if (d4 + 1 < D_DATA / 4) {
#pragma unroll
                for (int k = 0; k < 4; ++k)
                    wn[k] = *(const float4*)&W1[(size_t)((d4 + 1) * 4 + k) * H_DIM + 4 * cg];
            }
            float4 hv[8];
#pragma unroll
            for (int i = 0; i < 8; ++i) hv[i] = hrow[i][d4];   // scalar pipe
#pragma unroll
            for (int i = 0; i < 8; ++i) {
                acc[i][0] += hv[i].x * wv[0].x + hv[i].y * wv[1].x + hv[i].z * wv[2].x + hv[i].w * wv[3].x;
                acc[i][1] += hv[i].x * wv[0].y + hv[i].y * wv[1].y + hv[i].z * wv[2].y + hv[i].w * wv[3].y;
                acc[i][2] += hv[i].x * wv[0].z + hv[i].y * wv[1].z + hv[i].z * wv[2].z + hv[i].w * wv[3].z;
                acc[i][3] += hv[i].x * wv[0].w + hv[i].y * wv[1].w + hv[i].z * wv[2].w + hv[i].w * wv[3].w;
            }
#pragma unroll
            for (int k = 0; k < 4; ++k) wv[k] = wn[k];
        }
#pragma unroll
        for (int i = 0; i < 8; ++i) {
            float4 t;
            t.x = fmaxf(acc[i][0], 0.f); t.y = fmaxf(acc[i][1], 0.f);
            t.z = fmaxf(acc[i][2], 0.f); t.w = fmaxf(acc[i][3], 0.f);
            *(float4*)&zs[ng * 8 + i][4 * cg] = t;
        }
    }
    __syncthreads();

    // ---- phase 2: out = z @ W2 + b2 ----
    {
        int cg2 = tid >> 4;
        int ng2 = tid & 15;
        int col0 = cg2 * 3;
        int nA = ng2, nB = ng2 + 16;   // lane stride 260 dwords: 2-way (free)
        float acc2[2][3];
#pragma unroll
        for (int cc = 0; cc < 3; ++cc) {
            int c = col0 + cc;
            float bb = (c < N_CLS) ? b2[c] : 0.f;
            acc2[0][cc] = bb; acc2[1][cc] = bb;
        }
        for (int j4 = 0; j4 < H_DIM / 4; ++j4) {
            float4 z0 = *(const float4*)&zs[nA][j4 * 4];
            float4 z1 = *(const float4*)&zs[nB][j4 * 4];
#pragma unroll
            for (int cc = 0; cc < 3; ++cc) {
                float4 w = *(const float4*)&W2t[(size_t)(col0 + cc) * H_DIM + j4 * 4];
                acc2[0][cc] += z0.x * w.x + z0.y * w.y + z0.z * w.z + z0.w * w.w;
                acc2[1][cc] += z1.x * w.x + z1.y * w.y + z1.z * w.z + z1.w * w.w;
            }
        }
#pragma unroll
        for (int n = 0; n < 2; ++n)
#pragma unroll
            for (int cc = 0; cc < 3; ++cc) {
                int c = col0 + cc;
                int gn = node0 + (n == 0 ? nA : nB);
                if (c < N_CLS && gn < n_nodes)
                    out[(size_t)gn * N_CLS + c] = acc2[n][cc];
            }
    }
}

// ---------------- launch ----------------

static inline size_t align_up(size_t v, size_t a) { return (v + a - 1) & ~(a - 1); }

extern "C" void kernel_launch(void* const* d_in, const int* in_sizes, int n_in,
                              void* d_out, int out_size, void* d_ws, size_t ws_size,
                              hipStream_t stream) {
    const float* x   = (const float*)d_in[0];
    const int*   src = (const int*)d_in[1];
    const int*   dst = (const int*)d_in[2];
    const float* W1  = (const float*)d_in[3];
    const float* b1  = (const float*)d_in[4];
    const float* W2  = (const float*)d_in[5];
    const float* b2  = (const float*)d_in[6];
    float* out = (float*)d_out;

    char* p = (char*)d_ws;
    size_t off = 0;
    int* deg = (int*)(p + off);           off = align_up(off + N_NODES * 4, 256);
    int* row_ptr = (int*)(p + off);       off = align_up(off + (N_NODES + 1) * 4, 256);
    int* fill = (int*)(p + off);          off = align_up(off + N_NODES * 4, 256);
    float* norm = (float*)(p + off);      off = align_up(off + N_NODES * 4, 256);
    int* partials = (int*)(p + off);      off = align_up(off + SCAN_NB * 4, 256);
    int* pofs = (int*)(p + off);          off = align_up(off + SCAN_NB * 4, 256);
    float2* ew = (float2*)(p + off);      off = align_up(off + (size_t)EW_CAP * 8, 256);
    __half* x16 = (__half*)(p + off);     size_t x16_off = off;
                                          off = align_up(off + (size_t)N_NODES * HS * 2, 256);
    __half* h16B = (__half*)(p + off);    off = align_up(off + (size_t)N_NODES * HS * 2, 256);
    __half* h16A = (__half*)(p + off);    off = align_up(off + (size_t)N_NODES * HS * 2, 256);
    float* hF = (float*)(p + x16_off);    // fp32 dense overlays [x16, h16B] once dead
    (void)ws_size;
    float* W2t = (float*)fill;   // fill is dead after scatter_kernel

    hipMemsetAsync(deg, 0, N_NODES * 4, stream);
    hipMemsetAsync(fill, 0, N_NODES * 4, stream);

    int eb = (N_EDGES + 255) / 256;
    deg_kernel<<<eb, 256, 0, stream>>>(dst, deg, N_EDGES);
    scan_partial_kernel<<<SCAN_NB, 256, 0, stream>>>(deg, partials);
    scan_top_kernel<<<1, 256, 0, stream>>>(partials, pofs, row_ptr);
    scan_emit_kernel<<<SCAN_NB, 256, 0, stream>>>(deg, pofs, row_ptr, norm);
    scatter_kernel<<<eb, 256, 0, stream>>>(src, dst, norm, row_ptr, fill, ew, N_EDGES);
    pad_kernel<<<(N_NODES + 255) / 256, 256, 0, stream>>>(deg, row_ptr, ew, N_NODES);
    transpose_w2_kernel<<<(48 * H_DIM + 255) / 256, 256, 0, stream>>>(W2, W2t);

    int nh2 = N_NODES * HS / 2;
    convert_x16_kernel<<<(nh2 + 255) / 256, 256, 0, stream>>>(x, (__half2*)x16, nh2);

    int pb = (N_NODES / NPW) / 4;   // 12500 waves, 4 per block -> 3125 blocks
    prop16_kernel<<<pb, 256, 0, stream>>>(x16, x, row_ptr, ew, h16A, N_NODES);
    const __half* hin = h16A;
    for (int k = 1; k < K_STEPS - 1; ++k) {
        __half* ho = (k & 1) ? h16B : h16A;
        prop16_kernel<<<pb, 256, 0, stream>>>(hin, x, row_ptr, ew, ho, N_NODES);
        hin = ho;
    }
    // after k=8 (even), hin == h16A; k=9 writes fp32 dense hF
    prop_final_kernel<<<pb, 256, 0, stream>>>(hin, x, row_ptr, ew, hF, N_NODES);

    int mb = N_NODES / TN;
    mlp_kernel<<<mb, 256, 0, stream>>>(hF, W1, b1, W2t, b2, out, N_NODES);
}

// Round 9
// 620.442 us; speedup vs baseline: 1.2183x; 1.2183x over previous
//
#include <hip/hip_runtime.h>
#include <hip/hip_fp16.h>

// APPNP: K steps of D^{-1/2} A D^{-1/2} propagation + teleport, then MLP.
// R9: prop reverted to R7 (R8's streaming pipeline cut gathers-in-flight 8->4
// and regressed). MLP rewritten on MFMA f16 16x16x32: h kept fp16 stride-128
// (K=128, zero-padded) through ALL 10 steps; W1/W2 pre-packed into B-fragment
// order; z staged per-wave in LDS (no barrier); 88 MFMAs/wave total.

#define N_NODES 100000
#define N_PAD   100032   // h16 rows allocated (MLP tile overrun slack)
#define N_EDGES 800000
#define D_DATA  100
#define H_DIM   256
#define N_CLS   47
#define K_STEPS 10
#define ALPHA   0.1f
#define HS      128      // fp16 h row stride (halfs); cols 100..127 are zero
#define MB      64       // nodes per MLP block

#define SCAN_NB    200
#define SCAN_CHUNK 500   // 200*500 == N_NODES
#define EW_CAP (N_EDGES + 3 * N_NODES)

typedef _Float16 half8_t __attribute__((ext_vector_type(8)));
typedef float floatx4 __attribute__((ext_vector_type(4)));

// ---------------- CSR build ----------------

__global__ void deg_kernel(const int* __restrict__ dst, int* __restrict__ deg, int e) {
    int i = blockIdx.x * blockDim.x + threadIdx.x;
    if (i < e) atomicAdd(&deg[dst[i]], 1);
}

__global__ __launch_bounds__(256) void scan_partial_kernel(
        const int* __restrict__ deg, int* __restrict__ partials) {
    __shared__ int red[256];
    int t = threadIdx.x;
    int base = blockIdx.x * SCAN_CHUNK;
    int s = 0;
    int i0 = 2 * t, i1 = 2 * t + 1;
    if (i0 < SCAN_CHUNK) s += (deg[base + i0] + 3) & ~3;
    if (i1 < SCAN_CHUNK) s += (deg[base + i1] + 3) & ~3;
    red[t] = s;
    __syncthreads();
    for (int off = 128; off > 0; off >>= 1) {
        if (t < off) red[t] += red[t + off];
        __syncthreads();
    }
    if (t == 0) partials[blockIdx.x] = red[0];
}

__global__ __launch_bounds__(256) void scan_top_kernel(
        const int* __restrict__ partials, int* __restrict__ pofs,
        int* __restrict__ row_ptr) {
    __shared__ int s[256];
    int t = threadIdx.x;
    s[t] = (t < SCAN_NB) ? partials[t] : 0;
    __syncthreads();
    for (int off = 1; off < 256; off <<= 1) {
        int v = (t >= off) ? s[t - off] : 0;
        __syncthreads();
        s[t] += v;
        __syncthreads();
    }
    if (t < SCAN_NB) pofs[t] = s[t] - partials[t];
    if (t == SCAN_NB - 1) row_ptr[N_NODES] = s[t];   // padded total
}

__global__ __launch_bounds__(256) void scan_emit_kernel(
        const int* __restrict__ deg, const int* __restrict__ pofs,
        int* __restrict__ row_ptr, float* __restrict__ norm) {
    __shared__ int s[256];
    int t = threadIdx.x;
    int base = blockIdx.x * SCAN_CHUNK;
    int i0 = 2 * t, i1 = 2 * t + 1;
    int d0 = (i0 < SCAN_CHUNK) ? deg[base + i0] : 0;
    int d1 = (i1 < SCAN_CHUNK) ? deg[base + i1] : 0;
    int p0 = (d0 + 3) & ~3, p1 = (d1 + 3) & ~3;
    s[t] = p0 + p1;
    __syncthreads();
    for (int off = 1; off < 256; off <<= 1) {
        int v = (t >= off) ? s[t - off] : 0;
        __syncthreads();
        s[t] += v;
        __syncthreads();
    }
    int p = s[t] - (p0 + p1) + pofs[blockIdx.x];
    if (i0 < SCAN_CHUNK) {
        row_ptr[base + i0] = p;
        norm[base + i0] = rsqrtf((float)max(d0, 1));
    }
    if (i1 < SCAN_CHUNK) {
        row_ptr[base + i1] = p + p0;
        norm[base + i1] = rsqrtf((float)max(d1, 1));
    }
}

__global__ void scatter_kernel(const int* __restrict__ src, const int* __restrict__ dst,
                               const float* __restrict__ norm,
                               const int* __restrict__ row_ptr, int* __restrict__ fill,
                               float2* __restrict__ ew, int e) {
    int i = blockIdx.x * blockDim.x + threadIdx.x;
    if (i < e) {
        int d = dst[i], s = src[i];
        int pos = row_ptr[d] + atomicAdd(&fill[d], 1);
        float w = (1.0f - ALPHA) * norm[s] * norm[d];
        ew[pos] = make_float2(w, __int_as_float(s));
    }
}

__global__ void pad_kernel(const int* __restrict__ deg, const int* __restrict__ row_ptr,
                           float2* __restrict__ ew, int n) {
    int i = blockIdx.x * blockDim.x + threadIdx.x;
    if (i < n) {
        int b = row_ptr[i] + deg[i];
        int e = row_ptr[i + 1];
        for (int s = b; s < e; ++s) ew[s] = make_float2(0.f, __int_as_float(0));
    }
}

// W1 [100][256] fp32 -> W1p: MFMA B-frags, 16 n-tiles x 4 k-steps, K padded 128.
// Frag (nt,ks): lane holds B[k=ks*32+(lane>>4)*8+j][n=nt*16+(lane&15)], j=0..7.
__global__ void pack_w1_kernel(const float* __restrict__ W1, __half* __restrict__ W1p) {
    int idx = blockIdx.x * blockDim.x + threadIdx.x;   // 32768 halfs
    if (idx >= 16 * 4 * 64 * 8) return;
    int j = idx & 7;
    int lane = (idx >> 3) & 63;
    int ks = (idx >> 9) & 3;
    int nt = idx >> 11;
    int k = ks * 32 + (lane >> 4) * 8 + j;
    int n = nt * 16 + (lane & 15);
    float v = (k < D_DATA) ? W1[(size_t)k * H_DIM + n] : 0.f;
    W1p[idx] = __float2half(v);
}

// W2 [256][47] fp32 -> W2p: 3 n-tiles x 8 k-steps, N padded 48.
__global__ void pack_w2_kernel(const float* __restrict__ W2, __half* __restrict__ W2p) {
    int idx = blockIdx.x * blockDim.x + threadIdx.x;   // 12288 halfs
    if (idx >= 3 * 8 * 64 * 8) return;
    int j = idx & 7;
    int lane = (idx >> 3) & 63;
    int ks = (idx >> 9) & 7;
    int nt = idx >> 12;
    int k = ks * 32 + (lane >> 4) * 8 + j;
    int n = nt * 16 + (lane & 15);
    float v = (n < N_CLS) ? W2[(size_t)k * N_CLS + n] : 0.f;
    W2p[idx] = __float2half(v);
}

// x (fp32, dense stride 100) -> x16 (fp16, stride 128, zero pad cols)
__global__ void convert_x16_kernel(const float* __restrict__ x,
                                   __half2* __restrict__ x16, int n_half2) {
    int i = blockIdx.x * blockDim.x + threadIdx.x;
    if (i < n_half2) {
        int node = i >> 6;          // 64 half2 per row
        int c2 = i & 63;
        float2 v = make_float2(0.f, 0.f);
        if (c2 < D_DATA / 2) {
            const float2* r = (const float2*)(x + (size_t)node * D_DATA);
            v = r[c2];
        }
        x16[i] = __float22half2_rn(v);
    }
}

// ---------------- propagation (R7 structure, fp16 in/out) ----------------
// One wave per node; all 64 lanes: lane l holds half2 l of the 256B row.
// Padded CSR -> exact 8-wide then 4-wide batches, no scalar tail.

__global__ __launch_bounds__(256) void prop16_kernel(
        const __half* __restrict__ hin, const float* __restrict__ x,
        const int* __restrict__ row_ptr, const float2* __restrict__ ew,
        __half* __restrict__ hout, int n_nodes) {
    int lane = threadIdx.x & 63;
    int node = __builtin_amdgcn_readfirstlane(blockIdx.x * 4 + (threadIdx.x >> 6));
    if (node >= n_nodes) return;
    int beg = __builtin_amdgcn_readfirstlane(row_ptr[node]);
    int end = __builtin_amdgcn_readfirstlane(row_ptr[node + 1]);
    float ax = 0.f, ay = 0.f, bx = 0.f, by = 0.f;
    float cx = 0.f, cy = 0.f, dx = 0.f, dy = 0.f;
    int e = beg;
    for (; e + 8 <= end; e += 8) {
        float2 p[8];
#pragma unroll
        for (int j = 0; j < 8; ++j) p[j] = ew[e + j];          // uniform -> s_load
        __half2 hv[8];
#pragma unroll
        for (int j = 0; j < 8; ++j) {
            const __half2* r = (const __half2*)(hin + (size_t)__float_as_int(p[j].y) * HS);
            hv[j] = r[lane];
        }
        float2 v[8];
#pragma unroll
        for (int j = 0; j < 8; ++j) v[j] = __half22float2(hv[j]);
        ax += p[0].x * v[0].x; ay += p[0].x * v[0].y;
        bx += p[1].x * v[1].x; by += p[1].x * v[1].y;
        cx += p[2].x * v[2].x; cy += p[2].x * v[2].y;
        dx += p[3].x * v[3].x; dy += p[3].x * v[3].y;
        ax += p[4].x * v[4].x; ay += p[4].x * v[4].y;
        bx += p[5].x * v[5].x; by += p[5].x * v[5].y;
        cx += p[6].x * v[6].x; cy += p[6].x * v[6].y;
        dx += p[7].x * v[7].x; dy += p[7].x * v[7].y;
    }
    if (e < end) {   // exactly one 4-batch (padded deg % 4 == 0)
        float2 p[4];
#pragma unroll
        for (int j = 0; j < 4; ++j) p[j] = ew[e + j];
        __half2 hv[4];
#pragma unroll
        for (int j = 0; j < 4; ++j) {
            const __half2* r = (const __half2*)(hin + (size_t)__float_as_int(p[j].y) * HS);
            hv[j] = r[lane];
        }
#pragma unroll
        for (int j = 0; j < 4; ++j) {
            float2 v = __half22float2(hv[j]);
            ax += p[j].x * v.x; ay += p[j].x * v.y;
        }
    }
    float sx = (ax + bx) + (cx + dx);
    float sy = (ay + by) + (cy + dy);
    float2 xv = make_float2(0.f, 0.f);
    if (lane < D_DATA / 2)
        xv = ((const float2*)(x + (size_t)node * D_DATA))[lane];
    float2 o = make_float2(sx + ALPHA * xv.x, sy + ALPHA * xv.y);
    ((__half2*)(hout + (size_t)node * HS))[lane] = __float22half2_rn(o);
}

// ---------------- MFMA MLP ----------------
// Block = 256 threads = 4 waves; MB=64 nodes (16 per wave). Phase 1:
// z = relu(h16 @ W1 + b1) via 64 MFMAs (16 n-tiles x K=128/32), staged to the
// wave's own LDS rows (no barrier). Phase 2: out = z @ W2 + b2 via 24 MFMAs.
// Fragment maps (verified, guide §3): A[m=lane&15][k=quad*8+j];
// B[k=quad*8+j][n=lane&15]; D[row=quad*4+reg][col=lane&15].

#define ZP 264   // LDS z row stride in halfs (528B == 132 dwords == 4 mod 32)

__global__ __launch_bounds__(256, 4) void mlp_mfma_kernel(
        const __half* __restrict__ h16,
        const __half* __restrict__ W1p, const float* __restrict__ b1,
        const __half* __restrict__ W2p, const float* __restrict__ b2,
        float* __restrict__ out, int n_nodes) {
    __shared__ _Float16 zs[MB][ZP];   // 33 KB -> 4 blocks/CU
    int tid = threadIdx.x;
    int lane = tid & 63;
    int w = tid >> 6;
    int q = lane >> 4;
    int r = lane & 15;
    int node0 = blockIdx.x * MB + w * 16;   // this wave's 16 rows

    // phase-1 A-frags: K=128 in 4 k-steps; one 16B load each (rows 256B-aligned)
    half8_t a1[4];
#pragma unroll
    for (int ks = 0; ks < 4; ++ks)
        a1[ks] = *(const half8_t*)(h16 + (size_t)(node0 + r) * HS + ks * 32 + q * 8);

    const half8_t* w1f = (const half8_t*)W1p;
#pragma unroll 4
    for (int nt = 0; nt < 16; ++nt) {
        floatx4 acc = {0.f, 0.f, 0.f, 0.f};
#pragma unroll
        for (int ks = 0; ks < 4; ++ks) {
            half8_t b = w1f[(nt * 4 + ks) * 64 + lane];
            acc = __builtin_amdgcn_mfma_f32_16x16x32_f16(a1[ks], b, acc, 0, 0, 0);
        }
        float bb = b1[nt * 16 + r];
#pragma unroll
        for (int reg = 0; reg < 4; ++reg) {
            float zv = fmaxf(acc[reg] + bb, 0.f);
            zs[w * 16 + q * 4 + reg][nt * 16 + r] = (_Float16)zv;
        }
    }

    // phase-2 A-frags from own-wave LDS rows (m = r), K=256 in 8 k-steps
    half8_t a2[8];
#pragma unroll
    for (int ks = 0; ks < 8; ++ks)
        a2[ks] = *(const half8_t*)&zs[w * 16 + r][ks * 32 + q * 8];

    const half8_t* w2f = (const half8_t*)W2p;
#pragma unroll
    for (int nt = 0; nt < 3; ++nt) {
        floatx4 acc = {0.f, 0.f, 0.f, 0.f};
#pragma unroll
        for (int ks = 0; ks < 8; ++ks) {
            half8_t b = w2f[(nt * 8 + ks) * 64 + lane];
            acc = __builtin_amdgcn_mfma_f32_16x16x32_f16(a2[ks], b, acc, 0, 0, 0);
        }
        int c = nt * 16 + r;
        if (c < N_CLS) {
            float bb = b2[c];
#pragma unroll
            for (int reg = 0; reg < 4; ++reg) {
                int node = node0 + q * 4 + reg;
                if (node < n_nodes)
                    out[(size_t)node * N_CLS + c] = acc[reg] + bb;
            }
        }
    }
}

// ---------------- launch ----------------

static inline size_t align_up(size_t v, size_t a) { return (v + a - 1) & ~(a - 1); }

extern "C" void kernel_launch(void* const* d_in, const int* in_sizes, int n_in,
                              void* d_out, int out_size, void* d_ws, size_t ws_size,
                              hipStream_t stream) {
    const float* x   = (const float*)d_in[0];
    const int*   src = (const int*)d_in[1];
    const int*   dst = (const int*)d_in[2];
    const float* W1  = (const float*)d_in[3];
    const float* b1  = (const float*)d_in[4];
    const float* W2  = (const float*)d_in[5];
    const float* b2  = (const float*)d_in[6];
    float* out = (float*)d_out;

    char* p = (char*)d_ws;
    size_t off = 0;
    int* deg = (int*)(p + off);           off = align_up(off + N_NODES * 4, 256);
    int* row_ptr = (int*)(p + off);       off = align_up(off + (N_NODES + 1) * 4, 256);
    int* fill = (int*)(p + off);          off = align_up(off + N_NODES * 4, 256);
    float* norm = (float*)(p + off);      off = align_up(off + N_NODES * 4, 256);
    int* partials = (int*)(p + off);      off = align_up(off + SCAN_NB * 4, 256);
    int* pofs = (int*)(p + off);          off = align_up(off + SCAN_NB * 4, 256);
    __half* W1p = (__half*)(p + off);     off = align_up(off + 16 * 4 * 64 * 8 * 2, 256);
    __half* W2p = (__half*)(p + off);     off = align_up(off + 3 * 8 * 64 * 8 * 2, 256);
    float2* ew = (float2*)(p + off);      off = align_up(off + (size_t)EW_CAP * 8, 256);
    __half* x16 = (__half*)(p + off);     off = align_up(off + (size_t)N_NODES * HS * 2, 256);
    __half* h16A = (__half*)(p + off);    off = align_up(off + (size_t)N_PAD * HS * 2, 256);
    __half* h16B = (__half*)(p + off);    off = align_up(off + (size_t)N_PAD * HS * 2, 256);
    (void)ws_size;

    hipMemsetAsync(deg, 0, N_NODES * 4, stream);
    hipMemsetAsync(fill, 0, N_NODES * 4, stream);

    int eb = (N_EDGES + 255) / 256;
    deg_kernel<<<eb, 256, 0, stream>>>(dst, deg, N_EDGES);
    scan_partial_kernel<<<SCAN_NB, 256, 0, stream>>>(deg, partials);
    scan_top_kernel<<<1, 256, 0, stream>>>(partials, pofs, row_ptr);
    scan_emit_kernel<<<SCAN_NB, 256, 0, stream>>>(deg, pofs, row_ptr, norm);
    scatter_kernel<<<eb, 256, 0, stream>>>(src, dst, norm, row_ptr, fill, ew, N_EDGES);
    pad_kernel<<<(N_NODES + 255) / 256, 256, 0, stream>>>(deg, row_ptr, ew, N_NODES);
    pack_w1_kernel<<<128, 256, 0, stream>>>(W1, W1p);
    pack_w2_kernel<<<48, 256, 0, stream>>>(W2, W2p);

    int nh2 = N_NODES * HS / 2;
    convert_x16_kernel<<<(nh2 + 255) / 256, 256, 0, stream>>>(x, (__half2*)x16, nh2);

    int pb = N_NODES / 4;   // 4 waves (nodes) per block
    prop16_kernel<<<pb, 256, 0, stream>>>(x16, x, row_ptr, ew, h16A, N_NODES);
    const __half* hin = h16A;
    for (int k = 1; k < K_STEPS; ++k) {
        __half* ho = (k & 1) ? h16B : h16A;
        prop16_kernel<<<pb, 256, 0, stream>>>(hin, x, row_ptr, ew, ho, N_NODES);
        hin = ho;
    }
    // after k=9, hin == h16B

    int mb = (N_NODES + MB - 1) / MB;   // 1563; garbage pad rows masked at store
    mlp_mfma_kernel<<<mb, 256, 0, stream>>>(hin, W1p, b1, W2p, b2, out, N_NODES);
}

// Round 10
// 612.973 us; speedup vs baseline: 1.2332x; 1.0122x over previous
//
#include <hip/hip_runtime.h>
#include <hip/hip_fp16.h>

// APPNP: K steps of D^{-1/2} A D^{-1/2} propagation + teleport, then MFMA MLP.
// R10: normalization folded into the state: h_hat = norm (.) h  =>  all edge
// weights are exactly 1. ew becomes a 4B src index (scatter bytes/lines halve,
// prop edge s_loads halve), mid-step teleport reads fp16 x_hat (25.6MB vs
// 40MB fp32), per-edge FMA -> add. Final step: h = (1-a)*norm*S + a*x (fp32 x).
// CSR pad edges target a dedicated zero row (index N_NODES).

#define N_NODES 100000
#define N_PAD   100032   // rows allocated (zero row at N_NODES + MLP slack)
#define N_EDGES 800000
#define D_DATA  100
#define H_DIM   256
#define N_CLS   47
#define K_STEPS 10
#define ALPHA   0.1f
#define HS      128      // fp16 row stride (halfs); cols 100..127 are zero
#define MB      64       // nodes per MLP block

#define SCAN_NB    200
#define SCAN_CHUNK 500   // 200*500 == N_NODES
#define EW_CAP (N_EDGES + 3 * N_NODES)

typedef _Float16 half8_t __attribute__((ext_vector_type(8)));
typedef float floatx4 __attribute__((ext_vector_type(4)));

// ---------------- CSR build ----------------

__global__ void deg_kernel(const int* __restrict__ dst, int* __restrict__ deg, int e) {
    int i = blockIdx.x * blockDim.x + threadIdx.x;
    if (i < e) atomicAdd(&deg[dst[i]], 1);
}

__global__ __launch_bounds__(256) void scan_partial_kernel(
        const int* __restrict__ deg, int* __restrict__ partials) {
    __shared__ int red[256];
    int t = threadIdx.x;
    int base = blockIdx.x * SCAN_CHUNK;
    int s = 0;
    int i0 = 2 * t, i1 = 2 * t + 1;
    if (i0 < SCAN_CHUNK) s += (deg[base + i0] + 3) & ~3;
    if (i1 < SCAN_CHUNK) s += (deg[base + i1] + 3) & ~3;
    red[t] = s;
    __syncthreads();
    for (int off = 128; off > 0; off >>= 1) {
        if (t < off) red[t] += red[t + off];
        __syncthreads();
    }
    if (t == 0) partials[blockIdx.x] = red[0];
}

__global__ __launch_bounds__(256) void scan_top_kernel(
        const int* __restrict__ partials, int* __restrict__ pofs,
        int* __restrict__ row_ptr) {
    __shared__ int s[256];
    int t = threadIdx.x;
    s[t] = (t < SCAN_NB) ? partials[t] : 0;
    __syncthreads();
    for (int off = 1; off < 256; off <<= 1) {
        int v = (t >= off) ? s[t - off] : 0;
        __syncthreads();
        s[t] += v;
        __syncthreads();
    }
    if (t < SCAN_NB) pofs[t] = s[t] - partials[t];
    if (t == SCAN_NB - 1) row_ptr[N_NODES] = s[t];   // padded total
}

__global__ __launch_bounds__(256) void scan_emit_kernel(
        const int* __restrict__ deg, const int* __restrict__ pofs,
        int* __restrict__ row_ptr, float* __restrict__ norm) {
    __shared__ int s[256];
    int t = threadIdx.x;
    int base = blockIdx.x * SCAN_CHUNK;
    int i0 = 2 * t, i1 = 2 * t + 1;
    int d0 = (i0 < SCAN_CHUNK) ? deg[base + i0] : 0;
    int d1 = (i1 < SCAN_CHUNK) ? deg[base + i1] : 0;
    int p0 = (d0 + 3) & ~3, p1 = (d1 + 3) & ~3;
    s[t] = p0 + p1;
    __syncthreads();
    for (int off = 1; off < 256; off <<= 1) {
        int v = (t >= off) ? s[t - off] : 0;
        __syncthreads();
        s[t] += v;
        __syncthreads();
    }
    int p = s[t] - (p0 + p1) + pofs[blockIdx.x];
    if (i0 < SCAN_CHUNK) {
        row_ptr[base + i0] = p;
        norm[base + i0] = rsqrtf((float)max(d0, 1));
    }
    if (i1 < SCAN_CHUNK) {
        row_ptr[base + i1] = p + p0;
        norm[base + i1] = rsqrtf((float)max(d1, 1));
    }
}

// scatter: edge -> src index only (weights are 1 in h_hat space)
__global__ void scatter_kernel(const int* __restrict__ src, const int* __restrict__ dst,
                               const int* __restrict__ row_ptr, int* __restrict__ fill,
                               int* __restrict__ es, int e) {
    int i = blockIdx.x * blockDim.x + threadIdx.x;
    if (i < e) {
        int d = dst[i];
        int pos = row_ptr[d] + atomicAdd(&fill[d], 1);
        es[pos] = src[i];
    }
}

// pad slots -> the zero row (index N_NODES)
__global__ void pad_kernel(const int* __restrict__ deg, const int* __restrict__ row_ptr,
                           int* __restrict__ es, int n) {
    int i = blockIdx.x * blockDim.x + threadIdx.x;
    if (i < n) {
        int b = row_ptr[i] + deg[i];
        int e = row_ptr[i + 1];
        for (int s = b; s < e; ++s) es[s] = N_NODES;
    }
}

// W1 [100][256] fp32 -> W1p: MFMA B-frags, 16 n-tiles x 4 k-steps, K padded 128.
__global__ void pack_w1_kernel(const float* __restrict__ W1, __half* __restrict__ W1p) {
    int idx = blockIdx.x * blockDim.x + threadIdx.x;   // 32768 halfs
    if (idx >= 16 * 4 * 64 * 8) return;
    int j = idx & 7;
    int lane = (idx >> 3) & 63;
    int ks = (idx >> 9) & 3;
    int nt = idx >> 11;
    int k = ks * 32 + (lane >> 4) * 8 + j;
    int n = nt * 16 + (lane & 15);
    float v = (k < D_DATA) ? W1[(size_t)k * H_DIM + n] : 0.f;
    W1p[idx] = __float2half(v);
}

// W2 [256][47] fp32 -> W2p: 3 n-tiles x 8 k-steps, N padded 48.
__global__ void pack_w2_kernel(const float* __restrict__ W2, __half* __restrict__ W2p) {
    int idx = blockIdx.x * blockDim.x + threadIdx.x;   // 12288 halfs
    if (idx >= 3 * 8 * 64 * 8) return;
    int j = idx & 7;
    int lane = (idx >> 3) & 63;
    int ks = (idx >> 9) & 7;
    int nt = idx >> 12;
    int k = ks * 32 + (lane >> 4) * 8 + j;
    int n = nt * 16 + (lane & 15);
    float v = (n < N_CLS) ? W2[(size_t)k * N_CLS + n] : 0.f;
    W2p[idx] = __float2half(v);
}

// x (fp32, dense) -> xhat16 = norm (.) x (fp16, stride 128, zero pads);
// row N_NODES is all zeros (gather target of CSR pad edges).
__global__ void convert_xhat_kernel(const float* __restrict__ x,
                                    const float* __restrict__ norm,
                                    __half2* __restrict__ xh, int n_half2) {
    int i = blockIdx.x * blockDim.x + threadIdx.x;
    if (i < n_half2) {
        int node = i >> 6;          // 64 half2 per row
        int c2 = i & 63;
        float2 v = make_float2(0.f, 0.f);
        if (node < N_NODES && c2 < D_DATA / 2) {
            float nn = norm[node];
            const float2* r = (const float2*)(x + (size_t)node * D_DATA);
            float2 xv = r[c2];
            v = make_float2(nn * xv.x, nn * xv.y);
        }
        xh[i] = __float22half2_rn(v);
    }
}

// zero row N_NODES of h16A and h16B
__global__ void zero_rows_kernel(__half2* __restrict__ a, __half2* __restrict__ b) {
    int i = threadIdx.x;   // 128 threads
    if (i < 64) a[(size_t)N_NODES * (HS / 2) + i] = __half2();
    else        b[(size_t)N_NODES * (HS / 2) + (i - 64)] = __half2();
}

// ---------------- propagation (h_hat space) ----------------
// One wave per node; lane l holds half2 l of the 256B row. Weightless gather:
// S[n] = sum of h_hat[src] rows; out = c*S + teleport. Padded CSR -> exact
// 8-wide then 4-wide batches.

__global__ __launch_bounds__(256) void prop_mid_kernel(
        const __half* __restrict__ hin, const __half* __restrict__ xhat,
        const float* __restrict__ norm, const int* __restrict__ row_ptr,
        const int* __restrict__ es, __half* __restrict__ hout, int n_nodes) {
    int lane = threadIdx.x & 63;
    int node = __builtin_amdgcn_readfirstlane(blockIdx.x * 4 + (threadIdx.x >> 6));
    if (node >= n_nodes) return;
    int beg = __builtin_amdgcn_readfirstlane(row_ptr[node]);
    int end = __builtin_amdgcn_readfirstlane(row_ptr[node + 1]);
    float nn = norm[node];                       // uniform -> s_load
    float c = (1.0f - ALPHA) * nn * nn;
    float ax = 0.f, ay = 0.f, bx = 0.f, by = 0.f;
    float cx = 0.f, cy = 0.f, dx = 0.f, dy = 0.f;
    int e = beg;
    for (; e + 8 <= end; e += 8) {
        int s[8];
#pragma unroll
        for (int j = 0; j < 8; ++j) s[j] = es[e + j];          // uniform -> s_load x8
        __half2 hv[8];
#pragma unroll
        for (int j = 0; j < 8; ++j)
            hv[j] = ((const __half2*)(hin + (size_t)s[j] * HS))[lane];
        float2 v[8];
#pragma unroll
        for (int j = 0; j < 8; ++j) v[j] = __half22float2(hv[j]);
        ax += v[0].x; ay += v[0].y;  bx += v[1].x; by += v[1].y;
        cx += v[2].x; cy += v[2].y;  dx += v[3].x; dy += v[3].y;
        ax += v[4].x; ay += v[4].y;  bx += v[5].x; by += v[5].y;
        cx += v[6].x; cy += v[6].y;  dx += v[7].x; dy += v[7].y;
    }
    if (e < end) {   // exactly one 4-batch (padded deg % 4 == 0)
        int s[4];
#pragma unroll
        for (int j = 0; j < 4; ++j) s[j] = es[e + j];
        __half2 hv[4];
#pragma unroll
        for (int j = 0; j < 4; ++j)
            hv[j] = ((const __half2*)(hin + (size_t)s[j] * HS))[lane];
#pragma unroll
        for (int j = 0; j < 4; ++j) {
            float2 v = __half22float2(hv[j]);
            ax += v.x; ay += v.y;
        }
    }
    float sx = (ax + bx) + (cx + dx);
    float sy = (ay + by) + (cy + dy);
    // teleport: alpha * xhat (branchless 64-lane fp16 read; pad cols zero)
    float2 t = __half22float2(((const __half2*)(xhat + (size_t)node * HS))[lane]);
    float2 o = make_float2(c * sx + ALPHA * t.x, c * sy + ALPHA * t.y);
    ((__half2*)(hout + (size_t)node * HS))[lane] = __float22half2_rn(o);
}

// final step: h = (1-alpha)*norm*S + alpha*x  (exact fp32 teleport)
__global__ __launch_bounds__(256) void prop_final_kernel(
        const __half* __restrict__ hin, const float* __restrict__ x,
        const float* __restrict__ norm, const int* __restrict__ row_ptr,
        const int* __restrict__ es, __half* __restrict__ hout, int n_nodes) {
    int lane = threadIdx.x & 63;
    int node = __builtin_amdgcn_readfirstlane(blockIdx.x * 4 + (threadIdx.x >> 6));
    if (node >= n_nodes) return;
    int beg = __builtin_amdgcn_readfirstlane(row_ptr[node]);
    int end = __builtin_amdgcn_readfirstlane(row_ptr[node + 1]);
    float nn = norm[node];
    float c = (1.0f - ALPHA) * nn;
    float ax = 0.f, ay = 0.f, bx = 0.f, by = 0.f;
    float cx = 0.f, cy = 0.f, dx = 0.f, dy = 0.f;
    int e = beg;
    for (; e + 8 <= end; e += 8) {
        int s[8];
#pragma unroll
        for (int j = 0; j < 8; ++j) s[j] = es[e + j];
        __half2 hv[8];
#pragma unroll
        for (int j = 0; j < 8; ++j)
            hv[j] = ((const __half2*)(hin + (size_t)s[j] * HS))[lane];
        float2 v[8];
#pragma unroll
        for (int j = 0; j < 8; ++j) v[j] = __half22float2(hv[j]);
        ax += v[0].x; ay += v[0].y;  bx += v[1].x; by += v[1].y;
        cx += v[2].x; cy += v[2].y;  dx += v[3].x; dy += v[3].y;
        ax += v[4].x; ay += v[4].y;  bx += v[5].x; by += v[5].y;
        cx += v[6].x; cy += v[6].y;  dx += v[7].x; dy += v[7].y;
    }
    if (e < end) {
        int s[4];
#pragma unroll
        for (int j = 0; j < 4; ++j) s[j] = es[e + j];
        __half2 hv[4];
#pragma unroll
        for (int j = 0; j < 4; ++j)
            hv[j] = ((const __half2*)(hin + (size_t)s[j] * HS))[lane];
#pragma unroll
        for (int j = 0; j < 4; ++j) {
            float2 v = __half22float2(hv[j]);
            ax += v.x; ay += v.y;
        }
    }
    float sx = (ax + bx) + (cx + dx);
    float sy = (ay + by) + (cy + dy);
    float2 xv = make_float2(0.f, 0.f);
    if (lane < D_DATA / 2)
        xv = ((const float2*)(x + (size_t)node * D_DATA))[lane];
    float2 o = make_float2(c * sx + ALPHA * xv.x, c * sy + ALPHA * xv.y);
    ((__half2*)(hout + (size_t)node * HS))[lane] = __float22half2_rn(o);
}

// ---------------- MFMA MLP (unchanged from R9) ----------------

#define ZP 264

__global__ __launch_bounds__(256, 4) void mlp_mfma_kernel(
        const __half* __restrict__ h16,
        const __half* __restrict__ W1p, const float* __restrict__ b1,
        const __half* __restrict__ W2p, const float* __restrict__ b2,
        float* __restrict__ out, int n_nodes) {
    __shared__ _Float16 zs[MB][ZP];   // 33 KB -> 4 blocks/CU
    int tid = threadIdx.x;
    int lane = tid & 63;
    int w = tid >> 6;
    int q = lane >> 4;
    int r = lane & 15;
    int node0 = blockIdx.x * MB + w * 16;

    half8_t a1[4];
#pragma unroll
    for (int ks = 0; ks < 4; ++ks)
        a1[ks] = *(const half8_t*)(h16 + (size_t)(node0 + r) * HS + ks * 32 + q * 8);

    const half8_t* w1f = (const half8_t*)W1p;
#pragma unroll 4
    for (int nt = 0; nt < 16; ++nt) {
        floatx4 acc = {0.f, 0.f, 0.f, 0.f};
#pragma unroll
        for (int ks = 0; ks < 4; ++ks) {
            half8_t b = w1f[(nt * 4 + ks) * 64 + lane];
            acc = __builtin_amdgcn_mfma_f32_16x16x32_f16(a1[ks], b, acc, 0, 0, 0);
        }
        float bb = b1[nt * 16 + r];
#pragma unroll
        for (int reg = 0; reg < 4; ++reg) {
            float zv = fmaxf(acc[reg] + bb, 0.f);
            zs[w * 16 + q * 4 + reg][nt * 16 + r] = (_Float16)zv;
        }
    }

    half8_t a2[8];
#pragma unroll
    for (int ks = 0; ks < 8; ++ks)
        a2[ks] = *(const half8_t*)&zs[w * 16 + r][ks * 32 + q * 8];

    const half8_t* w2f = (const half8_t*)W2p;
#pragma unroll
    for (int nt = 0; nt < 3; ++nt) {
        floatx4 acc = {0.f, 0.f, 0.f, 0.f};
#pragma unroll
        for (int ks = 0; ks < 8; ++ks) {
            half8_t b = w2f[(nt * 8 + ks) * 64 + lane];
            acc = __builtin_amdgcn_mfma_f32_16x16x32_f16(a2[ks], b, acc, 0, 0, 0);
        }
        int c = nt * 16 + r;
        if (c < N_CLS) {
            float bb = b2[c];
#pragma unroll
            for (int reg = 0; reg < 4; ++reg) {
                int node = node0 + q * 4 + reg;
                if (node < n_nodes)
                    out[(size_t)node * N_CLS + c] = acc[reg] + bb;
            }
        }
    }
}

// ---------------- launch ----------------

static inline size_t align_up(size_t v, size_t a) { return (v + a - 1) & ~(a - 1); }

extern "C" void kernel_launch(void* const* d_in, const int* in_sizes, int n_in,
                              void* d_out, int out_size, void* d_ws, size_t ws_size,
                              hipStream_t stream) {
    const float* x   = (const float*)d_in[0];
    const int*   src = (const int*)d_in[1];
    const int*   dst = (const int*)d_in[2];
    const float* W1  = (const float*)d_in[3];
    const float* b1  = (const float*)d_in[4];
    const float* W2  = (const float*)d_in[5];
    const float* b2  = (const float*)d_in[6];
    float* out = (float*)d_out;

    char* p = (char*)d_ws;
    size_t off = 0;
    int* deg = (int*)(p + off);           off = align_up(off + N_NODES * 4, 256);
    int* row_ptr = (int*)(p + off);       off = align_up(off + (N_NODES + 1) * 4, 256);
    int* fill = (int*)(p + off);          off = align_up(off + N_NODES * 4, 256);
    float* norm = (float*)(p + off);      off = align_up(off + N_NODES * 4, 256);
    int* partials = (int*)(p + off);      off = align_up(off + SCAN_NB * 4, 256);
    int* pofs = (int*)(p + off);          off = align_up(off + SCAN_NB * 4, 256);
    __half* W1p = (__half*)(p + off);     off = align_up(off + 16 * 4 * 64 * 8 * 2, 256);
    __half* W2p = (__half*)(p + off);     off = align_up(off + 3 * 8 * 64 * 8 * 2, 256);
    int* es = (int*)(p + off);            off = align_up(off + (size_t)EW_CAP * 4, 256);
    __half* xhat = (__half*)(p + off);    off = align_up(off + (size_t)N_PAD * HS * 2, 256);
    __half* h16A = (__half*)(p + off);    off = align_up(off + (size_t)N_PAD * HS * 2, 256);
    __half* h16B = (__half*)(p + off);    off = align_up(off + (size_t)N_PAD * HS * 2, 256);
    (void)ws_size;

    hipMemsetAsync(deg, 0, N_NODES * 4, stream);
    hipMemsetAsync(fill, 0, N_NODES * 4, stream);

    int eb = (N_EDGES + 255) / 256;
    deg_kernel<<<eb, 256, 0, stream>>>(dst, deg, N_EDGES);
    scan_partial_kernel<<<SCAN_NB, 256, 0, stream>>>(deg, partials);
    scan_top_kernel<<<1, 256, 0, stream>>>(partials, pofs, row_ptr);
    scan_emit_kernel<<<SCAN_NB, 256, 0, stream>>>(deg, pofs, row_ptr, norm);
    scatter_kernel<<<eb, 256, 0, stream>>>(src, dst, row_ptr, fill, es, N_EDGES);
    pad_kernel<<<(N_NODES + 255) / 256, 256, 0, stream>>>(deg, row_ptr, es, N_NODES);
    pack_w1_kernel<<<128, 256, 0, stream>>>(W1, W1p);
    pack_w2_kernel<<<48, 256, 0, stream>>>(W2, W2p);

    int nh2 = (N_NODES + 1) * (HS / 2);   // includes the zero row
    convert_xhat_kernel<<<(nh2 + 255) / 256, 256, 0, stream>>>(x, norm, (__half2*)xhat, nh2);
    zero_rows_kernel<<<1, 128, 0, stream>>>((__half2*)h16A, (__half2*)h16B);

    int pb = N_NODES / 4;   // 4 waves (nodes) per block
    // k=0: xhat -> A; k=1..8 ping-pong (odd->B, even->A); k=9 final: A -> B
    prop_mid_kernel<<<pb, 256, 0, stream>>>(xhat, xhat, norm, row_ptr, es, h16A, N_NODES);
    const __half* hin = h16A;
    for (int k = 1; k < K_STEPS - 1; ++k) {
        __half* ho = (k & 1) ? h16B : h16A;
        prop_mid_kernel<<<pb, 256, 0, stream>>>(hin, xhat, norm, row_ptr, es, ho, N_NODES);
        hin = ho;
    }
    prop_final_kernel<<<pb, 256, 0, stream>>>(hin, x, norm, row_ptr, es, h16B, N_NODES);

    int mb = (N_NODES + MB - 1) / MB;
    mlp_mfma_kernel<<<mb, 256, 0, stream>>>(h16B, W1p, b1, W2p, b2, out, N_NODES);
}